// Round 1
// baseline (120.680 us; speedup 1.0000x reference)
//
#include <hip/hip_runtime.h>
#include <math.h>

__device__ __forceinline__ double rdin(const void* p, int idx, bool isdbl) {
  return isdbl ? ((const double*)p)[idx] : (double)((const float*)p)[idx];
}

__device__ __forceinline__ bool detect_dbl(const void* xv) {
  // f64 data reinterpreted as f32 words shows wild exponents in the low
  // (mantissa) words; true f32 N(0,1) never exceeds 1e6. 64 words => P(miss)~2e-8.
  const float* xq = (const float*)xv;
  bool isdbl = false;
  for (int j = 0; j < 64; ++j) {
    float a = fabsf(xq[j]);
    if (!(a < 1e6f)) isdbl = true;
  }
  return isdbl;
}

// ---------------------------------------------------------------------------
// Fused kernel: one wave (64 threads) per sample.
// Phase-1 math unchanged (build H analytically, 4-sweep complex Jacobi,
// Daleckii-Krein F, Jacobian column per thread). Then M = g^T (g/P) is
// staged in LDS (not global), and the SAME block streams out both
// I_b = M (16 KB) and I_k[j,k,l,m] = x_j x_l M[k,m] (256 KB) with
// wave-coalesced 1KB dwordx4 stores. Eliminates the phase-2 launch, the
// 4 MB global M round-trip, and the inter-kernel drain; write traffic
// stays at the 71.3 MB floor.
// ---------------------------------------------------------------------------
__global__ __launch_bounds__(64) void fi_fused(
    const void* __restrict__ xv,
    const void* __restrict__ kv,
    const void* __restrict__ bv,
    float* __restrict__ out, int Bn)
{
  const int i = blockIdx.x;
  const int t = threadIdx.x;           // 0..63

  __shared__ float pw[64];
  __shared__ float Hre[8][8], Him[8][8];
  __shared__ float Vre[8][8], Vim[8][8];
  __shared__ float Fre[8][8], Fim[8][8];
  __shared__ float Gre[8][8], Gim[8][8];
  __shared__ float ampre[8], ampim[8], invPs[8], ev[8];
  __shared__ __align__(16) float hk[64][8];    // h columns, k-major
  __shared__ __align__(16) float Ms[64][68];   // M rows, +68 stride (16B-aligned, breaks bank aliasing)

  const bool isdbl = detect_dbl(xv);

  // ---- pw = x @ K + bias ---------------------------------------------------
  {
    float acc = (float)rdin(bv, t, isdbl);
    #pragma unroll
    for (int j = 0; j < 4; ++j)
      acc += (float)rdin(xv, i*4 + j, isdbl) * (float)rdin(kv, j*64 + t, isdbl);
    pw[t] = acc;
  }
  __syncthreads();

  // ---- build H = sum_k pw_k P_k (analytic Pauli strings), init V = I ------
  {
    int r = t >> 3, c = t & 7;
    int m = r ^ c;
    float hre = 0.0f, him = 0.0f;
    for (int u = 0; u < 8; ++u) {
      int k = 0;
      float pr = 1.0f, pim = 0.0f;
      #pragma unroll
      for (int q = 0; q < 3; ++q) {
        int bit = 2 - q;
        int f  = (m >> bit) & 1;
        int ch = (u >> bit) & 1;
        int rb = (r >> bit) & 1;
        int d  = f ? (ch ? 2 : 1) : (ch ? 3 : 0);  // I=0,X=1,Y=2,Z=3
        k = (k << 2) | d;
        if (d == 2) {
          float nr = rb ? -pim : pim;
          float ni = rb ?  pr  : -pr;
          pr = nr; pim = ni;
        } else if (d == 3 && rb) { pr = -pr; pim = -pim; }
      }
      float w = pw[k];
      hre += w * pr; him += w * pim;
    }
    Hre[r][c] = hre; Him[r][c] = him;
    Vre[r][c] = (r == c) ? 1.0f : 0.0f;
    Vim[r][c] = 0.0f;
  }
  __syncthreads();

  // ---- complex Hermitian Jacobi, fp32, closed-form round-robin pairs ------
  const int tl = t & 31;
  const int pp = tl >> 3, j = tl & 7;
  #pragma unroll
  for (int sweep = 0; sweep < 4; ++sweep) {
    #pragma unroll
    for (int round = 0; round < 7; ++round) {
      // circle-method tournament: fix 7, rotate 0..6.  All-ALU, no loads.
      int p, q;
      if (pp == 0) { p = 7; q = round; }
      else {
        p = round + pp;     if (p >= 7) p -= 7;
        q = round + 7 - pp; if (q >= 7) q -= 7;
      }
      // rotation params + own column elements, one LDS wait
      float cc = 1.0f, sg = 0.0f, wr = 1.0f, wi = 0.0f;
      {
        float a = Hre[p][p], b = Hre[q][q];
        float zr = Hre[p][q], zi = Him[p][q];
        float r2 = zr*zr + zi*zi;
        if (r2 > 1e-24f) {
          float rr = sqrtf(r2);
          wr = zr / rr; wi = zi / rr;
          float th = (b - a) / (2.0f * rr);
          float tt = ((th >= 0.0f) ? 1.0f : -1.0f) / (fabsf(th) + sqrtf(1.0f + th*th));
          cc = 1.0f / sqrtf(1.0f + tt*tt);
          sg = tt * cc;
        }
      }
      float e0r, e0i, e1r, e1i;
      if (t < 32) { e0r = Hre[j][p]; e0i = Him[j][p]; e1r = Hre[j][q]; e1i = Him[j][q]; }
      else        { e0r = Vre[j][p]; e0i = Vim[j][p]; e1r = Vre[j][q]; e1i = Vim[j][q]; }
      __syncthreads();
      if (t < 32) {                      // H column update: A <- A*U
        Hre[j][p] = cc*e0r - sg*(wr*e1r + wi*e1i);
        Him[j][p] = cc*e0i - sg*(wr*e1i - wi*e1r);
        Hre[j][q] = sg*(wr*e0r - wi*e0i) + cc*e1r;
        Him[j][q] = sg*(wr*e0i + wi*e0r) + cc*e1i;
      } else {                           // V column update: V <- V*U
        Vre[j][p] = cc*e0r - sg*(wr*e1r + wi*e1i);
        Vim[j][p] = cc*e0i - sg*(wr*e1i - wi*e1r);
        Vre[j][q] = sg*(wr*e0r - wi*e0i) + cc*e1r;
        Vim[j][q] = sg*(wr*e0i + wi*e0r) + cc*e1i;
      }
      __syncthreads();
      if (t < 32) {                      // H row update: A <- U^H * A
        float rpr = Hre[p][j], rpi = Him[p][j];
        float rqr = Hre[q][j], rqi = Him[q][j];
        Hre[p][j] = cc*rpr - sg*(wr*rqr - wi*rqi);
        Him[p][j] = cc*rpi - sg*(wr*rqi + wi*rqr);
        Hre[q][j] = sg*(wr*rpr + wi*rpi) + cc*rqr;
        Him[q][j] = sg*(wr*rpi - wi*rpr) + cc*rqi;
      }
      __syncthreads();
    }
  }

  if (t < 8) ev[t] = Hre[t][t];
  __syncthreads();

  // ---- F (Daleckii-Krein) + amp + 1/P -------------------------------------
  {
    int s = t >> 3, u = t & 7;
    float dm = 0.5f * (ev[s] - ev[u]);
    float av = 0.5f * (ev[s] + ev[u]);
    float sc = (fabsf(dm) < 1e-3f) ? (1.0f - dm*dm*(1.0f/6.0f)) : (__sinf(dm)/dm);
    Fre[s][u] =  __cosf(av) * sc;
    Fim[s][u] = -__sinf(av) * sc;
  }
  if (t < 8) {
    float are = 0.0f, aim = 0.0f;
    #pragma unroll
    for (int s = 0; s < 8; ++s) {
      float ce = __cosf(ev[s]), se = -__sinf(ev[s]);
      float c0r = Vre[0][s], c0i = -Vim[0][s];
      float wr2 = c0r*ce - c0i*se;
      float wi2 = c0r*se + c0i*ce;
      float vjr = Vre[t][s], vji = Vim[t][s];
      are += vjr*wr2 - vji*wi2;
      aim += vjr*wi2 + vji*wr2;
    }
    ampre[t] = are; ampim[t] = aim;
    float P = are*are + aim*aim;
    invPs[t] = 1.0f / fmaxf(P, 1e-30f);
  }
  __syncthreads();

  // ---- G[s][rho] = sum_u V[rho][u] F[s][u] conj(V[0][u]) ------------------
  {
    int s = t >> 3, rho = t & 7;
    float gr = 0.0f, gi = 0.0f;
    #pragma unroll
    for (int u = 0; u < 8; ++u) {
      float c0r = Vre[0][u], c0i = -Vim[0][u];
      float fr = Fre[s][u], fi = Fim[s][u];
      float fcr = fr*c0r - fi*c0i;
      float fci = fr*c0i + fi*c0r;
      float vr = Vre[rho][u], vi = Vim[rho][u];
      gr += vr*fcr - vi*fci;
      gi += vr*fci + vi*fcr;
    }
    Gre[s][rho] = gr; Gim[s][rho] = gi;
  }
  __syncthreads();

  // ---- Jacobian column k = t: gcol[p] in registers, h to LDS --------------
  float gcol[8];
  {
    const int k = t;
    const int d0 = (k >> 4) & 3, d1 = (k >> 2) & 3, d2 = k & 3;
    const int m = ((((d0 == 1) | (d0 == 2)) ? 1 : 0) << 2)
                | ((((d1 == 1) | (d1 == 2)) ? 1 : 0) << 1)
                |  (((d2 == 1) | (d2 == 2)) ? 1 : 0);
    float yre[8], yim[8];
    #pragma unroll
    for (int s = 0; s < 8; ++s) { yre[s] = 0.0f; yim[s] = 0.0f; }
    #pragma unroll
    for (int r = 0; r < 8; ++r) {
      float pr = 1.0f, pim = 0.0f;       // ph_k(r), in {±1, ±i}
      const int dd0[3] = {d0, d1, d2};
      #pragma unroll
      for (int q = 0; q < 3; ++q) {
        int rb = (r >> (2 - q)) & 1;
        int d = dd0[q];
        if (d == 2) {
          float nr = rb ? -pim : pim;
          float ni = rb ?  pr  : -pr;
          pr = nr; pim = ni;
        } else if (d == 3 && rb) { pr = -pr; pim = -pim; }
      }
      int rm = r ^ m;
      #pragma unroll
      for (int s = 0; s < 8; ++s) {      // y_s += conj(V[r][s]) ph G[s][r^m]
        float vr = Vre[r][s], vi = -Vim[r][s];
        float gr2 = Gre[s][rm], gi2 = Gim[s][rm];
        float ar = pr*gr2 - pim*gi2;
        float ai = pr*gi2 + pim*gr2;
        yre[s] += vr*ar - vi*ai;
        yim[s] += vr*ai + vi*ar;
      }
    }
    #pragma unroll
    for (int p = 0; p < 8; ++p) {        // damp_p = sum_s V[p][s] * (-i*y_s)
      float dr = 0.0f, di = 0.0f;
      #pragma unroll
      for (int s = 0; s < 8; ++s) {
        float ysr =  yim[s], ysi = -yre[s];   // * (-i)
        float vr = Vre[p][s], vi = Vim[p][s];
        dr += vr*ysr - vi*ysi;
        di += vr*ysi + vi*ysr;
      }
      float gg = 2.0f * (ampre[p]*dr + ampim[p]*di);
      gcol[p] = gg;
      hk[k][p] = gg * invPs[p];
    }
  }

  // ---- per-lane x scale factors (issued before barrier to hide latency) ---
  const int lq  = t >> 4;               // l  = 0..3
  const int m4c = t & 15;               // m4 = 0..15
  float xsc[4];
  {
    float xl = (float)rdin(xv, i*4 + lq, isdbl);
    #pragma unroll
    for (int jj = 0; jj < 4; ++jj)
      xsc[jj] = xl * (float)rdin(xv, i*4 + jj, isdbl);
  }
  __syncthreads();

  // ---- M row t = gcol . h  ->  LDS (was: global I_b write) ----------------
  {
    #pragma unroll
    for (int m4 = 0; m4 < 16; ++m4) {
      float4 vv;
      #pragma unroll
      for (int l2 = 0; l2 < 4; ++l2) {
        int m = m4*4 + l2;
        const float4 ha = *(const float4*)&hk[m][0];   // broadcast reads
        const float4 hb = *(const float4*)&hk[m][4];
        float acc = gcol[0]*ha.x + gcol[1]*ha.y + gcol[2]*ha.z + gcol[3]*ha.w
                  + gcol[4]*hb.x + gcol[5]*hb.y + gcol[6]*hb.z + gcol[7]*hb.w;
        (&vv.x)[l2] = acc;
      }
      *(float4*)&Ms[t][m4*4] = vv;
    }
  }
  __syncthreads();

  // ---- I_b = M: 16 wave-coalesced 1KB stores ------------------------------
  {
    float* ob = out + (size_t)Bn * 65536 + (size_t)i * 4096;
    #pragma unroll
    for (int it = 0; it < 16; ++it) {
      int r = it*4 + lq;                 // lanes cover 4 consecutive rows
      float4 mv = *(const float4*)&Ms[r][m4c*4];
      *(float4*)(ob + (size_t)r * 64 + m4c*4) = mv;
    }
  }

  // ---- I_k[j,k,l,m] = x_j x_l M[k,m]: 256 wave-coalesced 1KB stores -------
  {
    // lane offset l*64 + m4*4 => each (k,j) store covers rows (j,k,0..3) = 1KB
    float* okl = out + (size_t)i * 65536 + (size_t)lq * 64 + (size_t)m4c * 4;
    #pragma unroll 4
    for (int k = 0; k < 64; ++k) {
      float4 mv = *(const float4*)&Ms[k][m4c*4];
      #pragma unroll
      for (int jj = 0; jj < 4; ++jj) {
        float s = xsc[jj];
        *(float4*)(okl + (size_t)jj * 16384 + (size_t)k * 256) =
            make_float4(s*mv.x, s*mv.y, s*mv.z, s*mv.w);
      }
    }
  }
}

extern "C" void kernel_launch(void* const* d_in, const int* in_sizes, int n_in,
                              void* d_out, int out_size, void* d_ws, size_t ws_size,
                              hipStream_t stream) {
  (void)n_in; (void)d_ws; (void)ws_size; (void)out_size;
  int Bn = in_sizes[0] / 4;   // 256
  fi_fused<<<Bn, 64, 0, stream>>>(d_in[0], d_in[1], d_in[2], (float*)d_out, Bn);
}